// Round 1
// baseline (663.290 us; speedup 1.0000x reference)
//
#include <hip/hip_runtime.h>
#include <hip/hip_bf16.h>

// Problem constants
#define L_SEQ   16384
#define D_IO    2048
#define HEADS   16
#define DHEAD   128

typedef __attribute__((ext_vector_type(8))) short short8;
typedef __attribute__((ext_vector_type(4))) float floatx4;

typedef const __attribute__((address_space(1))) unsigned int gu_t;
typedef __attribute__((address_space(3))) unsigned int lu_t;

__device__ __forceinline__ unsigned short f2bf(float f) {
  unsigned u = __float_as_uint(f);
  u += 0x7fffu + ((u >> 16) & 1u);   // RNE
  return (unsigned short)(u >> 16);
}
__device__ __forceinline__ float bf2f(unsigned short s) {
  return __uint_as_float(((unsigned)s) << 16);
}

// ---------------- f32 -> bf16 convert (vectorized, grid-stride) ----------------
__global__ __launch_bounds__(256)
void cvt_f32_bf16(const float* __restrict__ x, unsigned short* __restrict__ y, long n)
{
  for (long i = ((long)blockIdx.x * 256 + threadIdx.x) * 8; i < n;
       i += (long)gridDim.x * 256 * 8) {
    const float4 v0 = *(const float4*)(x + i);
    const float4 v1 = *(const float4*)(x + i + 4);
    uint4 r;
    r.x = (unsigned)f2bf(v0.x) | ((unsigned)f2bf(v0.y) << 16);
    r.y = (unsigned)f2bf(v0.z) | ((unsigned)f2bf(v0.w) << 16);
    r.z = (unsigned)f2bf(v1.x) | ((unsigned)f2bf(v1.y) << 16);
    r.w = (unsigned)f2bf(v1.z) | ((unsigned)f2bf(v1.w) << 16);
    *(uint4*)(y + i) = r;
  }
}

// ------------- transpose + convert: S[2048][2048] f32 -> D[2048][2048] bf16 (D = S^T) -------------
__global__ __launch_bounds__(256)
void transpose_cvt(const float* __restrict__ S, unsigned short* __restrict__ D)
{
  __shared__ float tile[32][33];           // +1 pad: conflict-free
  const int bn = blockIdx.x * 32;          // column in S (= output row)
  const int bk = blockIdx.y * 32;          // row in S
  const int tx = threadIdx.x, ty = threadIdx.y;  // (32, 8)
  #pragma unroll
  for (int i = 0; i < 32; i += 8)
    tile[ty + i][tx] = S[(size_t)(bk + ty + i) * D_IO + bn + tx];
  __syncthreads();
  #pragma unroll
  for (int i = 0; i < 32; i += 8)
    D[(size_t)(bn + ty + i) * D_IO + bk + tx] = f2bf(tile[tx][ty + i]);
}

// ---------------- 128x128-tile bf16 GEMM (m97 structure) ----------------
// A: [M][2048] bf16 row-major. B: [N][2048] bf16 row-major (i.e. B^T of the math GEMM).
// C = A * B^T. EPI=0: write bf16, EPI=1: write f32 + bias.
template<int EPI>
__global__ __launch_bounds__(256)
void gemm_bt(const unsigned short* __restrict__ A,
             const unsigned short* __restrict__ B,
             void* __restrict__ Cout,
             const float* __restrict__ bias,
             int ldc)
{
  __shared__ unsigned short Asm[128 * 32];   // 8 KB
  __shared__ unsigned short Bsm[128 * 32];   // 8 KB
  const int bn = blockIdx.x, bm = blockIdx.y;
  const int t = threadIdx.x, lane = t & 63, wave = t >> 6;
  const int wm = wave >> 1, wn = wave & 1;   // 2x2 wave grid, 64x64 per wave

  floatx4 acc[4][4];
  #pragma unroll
  for (int m = 0; m < 4; ++m)
    #pragma unroll
    for (int n = 0; n < 4; ++n) acc[m][n] = (floatx4)0.f;

  const unsigned short* Abase = A + (size_t)bm * 128 * 2048;
  const unsigned short* Bbase = B + (size_t)bn * 128 * 2048;

  // staging geometry: tile is [128][32] bf16 = 8192 B; 256 thr x 16 B = 4096 B per sweep, 2 sweeps.
  // flat byte f = wave*1024 + sweep*4096 + lane*16 ; row = f>>6 ; elem col = (f&63)>>1
  const int f0 = wave * 1024 + lane * 16;
  const int r0 = f0 >> 6;          // rows 0..63
  const int r1 = r0 + 64;          // rows 64..127
  const int c0 = (f0 & 63) >> 1;   // 0,8,16,24

  const int fr = lane & 15;             // fragment row/col within 16
  const int ko = (lane >> 4) * 8;       // k offset of this lane's 8 elems

  for (int kt = 0; kt < 2048 / 32; ++kt) {
    const int k0 = kt * 32;
    // global -> LDS direct, 16B/lane (dest = uniform base + lane*16)
    __builtin_amdgcn_global_load_lds((gu_t*)(Abase + (size_t)r0 * 2048 + k0 + c0),
                                     (lu_t*)(Asm + wave * 512), 16, 0, 0);
    __builtin_amdgcn_global_load_lds((gu_t*)(Abase + (size_t)r1 * 2048 + k0 + c0),
                                     (lu_t*)(Asm + wave * 512 + 2048), 16, 0, 0);
    __builtin_amdgcn_global_load_lds((gu_t*)(Bbase + (size_t)r0 * 2048 + k0 + c0),
                                     (lu_t*)(Bsm + wave * 512), 16, 0, 0);
    __builtin_amdgcn_global_load_lds((gu_t*)(Bbase + (size_t)r1 * 2048 + k0 + c0),
                                     (lu_t*)(Bsm + wave * 512 + 2048), 16, 0, 0);
    __syncthreads();   // drains vmcnt before barrier

    short8 av[4], bv[4];
    #pragma unroll
    for (int m = 0; m < 4; ++m)
      av[m] = *(const short8*)(Asm + (wm * 64 + m * 16 + fr) * 32 + ko);
    #pragma unroll
    for (int n = 0; n < 4; ++n)
      bv[n] = *(const short8*)(Bsm + (wn * 64 + n * 16 + fr) * 32 + ko);
    #pragma unroll
    for (int m = 0; m < 4; ++m)
      #pragma unroll
      for (int n = 0; n < 4; ++n)
        acc[m][n] = __builtin_amdgcn_mfma_f32_16x16x32_bf16(av[m], bv[n], acc[m][n], 0, 0, 0);
    __syncthreads();
  }

  // epilogue: C/D layout col = lane&15, row = (lane>>4)*4 + reg  [m89-verified]
  const int crow0 = bm * 128 + wm * 64 + (lane >> 4) * 4;
  const int ccol0 = bn * 128 + wn * 64 + (lane & 15);
  if (EPI == 0) {
    unsigned short* C = (unsigned short*)Cout;
    #pragma unroll
    for (int m = 0; m < 4; ++m)
      #pragma unroll
      for (int n = 0; n < 4; ++n)
        #pragma unroll
        for (int r = 0; r < 4; ++r)
          C[(size_t)(crow0 + m * 16 + r) * ldc + ccol0 + n * 16] = f2bf(acc[m][n][r]);
  } else {
    float* C = (float*)Cout;
    #pragma unroll
    for (int n = 0; n < 4; ++n) {
      const float bv_ = bias[ccol0 + n * 16];
      #pragma unroll
      for (int m = 0; m < 4; ++m)
        #pragma unroll
        for (int r = 0; r < 4; ++r)
          C[(size_t)(crow0 + m * 16 + r) * ldc + ccol0 + n * 16] = acc[m][n][r] + bv_;
    }
  }
}

// ---------------- sliding-window attention pool ----------------
// KV: [L][4096] bf16 (cols 0..2047 = K(h*128+d), 2048..4095 = V). Q: [16][128] f32.
// P: [L][2048] bf16 pooled output. One wave per (t, h); lane covers d = 2*lane, 2*lane+1.
__global__ __launch_bounds__(256)
void winpool(const unsigned short* __restrict__ KV,
             const float* __restrict__ Q,
             unsigned short* __restrict__ P)
{
  const int lane = threadIdx.x & 63, wid = threadIdx.x >> 6;
  const int t = blockIdx.x * 4 + wid;
  const int h = blockIdx.y;
  const float qx = Q[h * DHEAD + lane * 2];
  const float qy = Q[h * DHEAD + lane * 2 + 1];
  const float scale = 0.08838834764831845f;  // 1/sqrt(128)

  float s[4];
  #pragma unroll
  for (int w = 0; w < 4; ++w) {
    const int idx = t - 3 + w;
    float part = 0.f;
    if (idx >= 0) {
      const unsigned kk = *(const unsigned*)(KV + (size_t)idx * 4096 + h * DHEAD + lane * 2);
      part = qx * bf2f((unsigned short)(kk & 0xffffu)) +
             qy * bf2f((unsigned short)(kk >> 16));
    }
    #pragma unroll
    for (int off = 32; off > 0; off >>= 1) part += __shfl_xor(part, off);
    s[w] = part * scale;
  }
  float mx = -3.0e38f;
  #pragma unroll
  for (int w = 0; w < 4; ++w) if (t - 3 + w >= 0) mx = fmaxf(mx, s[w]);
  float p[4], sum = 0.f;
  #pragma unroll
  for (int w = 0; w < 4; ++w) {
    p[w] = (t - 3 + w >= 0) ? expf(s[w] - mx) : 0.f;
    sum += p[w];
  }
  const float inv = 1.f / sum;

  float o0 = 0.f, o1 = 0.f;
  #pragma unroll
  for (int w = 0; w < 4; ++w) {
    const int idx = t - 3 + w;
    if (idx >= 0) {
      const unsigned vv = *(const unsigned*)(KV + (size_t)idx * 4096 + 2048 + h * DHEAD + lane * 2);
      o0 += p[w] * bf2f((unsigned short)(vv & 0xffffu));
      o1 += p[w] * bf2f((unsigned short)(vv >> 16));
    }
  }
  o0 *= inv; o1 *= inv;
  const unsigned outw = ((unsigned)f2bf(o1) << 16) | (unsigned)f2bf(o0);
  *(unsigned*)(P + (size_t)t * D_IO + h * DHEAD + lane * 2) = outw;
}

// ---------------- launch ----------------
extern "C" void kernel_launch(void* const* d_in, const int* in_sizes, int n_in,
                              void* d_out, int out_size, void* d_ws, size_t ws_size,
                              hipStream_t stream)
{
  const float* e_seq = (const float*)d_in[0];
  const float* q     = (const float*)d_in[1];
  const float* Wk    = (const float*)d_in[2];
  const float* Wv    = (const float*)d_in[3];
  const float* Wo    = (const float*)d_in[4];
  const float* bo    = (const float*)d_in[5];
  float* out = (float*)d_out;

  // workspace layout (226.5 MB total)
  char* ws = (char*)d_ws;
  unsigned short* Ebf  = (unsigned short*)ws;                        // 67,108,864 B (E bf16; later reused as pooled)
  unsigned short* KV   = (unsigned short*)(ws + 67108864);           // 134,217,728 B
  unsigned short* Wkvt = (unsigned short*)(ws + 67108864 + 134217728);           // 16,777,216 B
  unsigned short* Wot  = (unsigned short*)(ws + 67108864 + 134217728 + 16777216); // 8,388,608 B

  cvt_f32_bf16<<<2048, 256, 0, stream>>>(e_seq, Ebf, (long)L_SEQ * D_IO);
  dim3 tb(32, 8);
  transpose_cvt<<<dim3(64, 64), tb, 0, stream>>>(Wk, Wkvt);
  transpose_cvt<<<dim3(64, 64), tb, 0, stream>>>(Wv, Wkvt + (size_t)D_IO * D_IO);
  transpose_cvt<<<dim3(64, 64), tb, 0, stream>>>(Wo, Wot);

  // KV = E * [Wk|Wv]   (M=16384, N=4096, K=2048)
  gemm_bt<0><<<dim3(32, 128), 256, 0, stream>>>(Ebf, Wkvt, KV, nullptr, 4096);

  // pooled (into Ebf, which is no longer needed)
  winpool<<<dim3(L_SEQ / 4, HEADS), 256, 0, stream>>>(KV, q, Ebf);

  // out = pooled * Wo + bo   (M=16384, N=2048, K=2048), f32 out
  gemm_bt<1><<<dim3(16, 128), 256, 0, stream>>>(Ebf, Wot, out, bo, 2048);
}

// Round 2
// 579.359 us; speedup vs baseline: 1.1449x; 1.1449x over previous
//
#include <hip/hip_runtime.h>
#include <hip/hip_bf16.h>

// Problem constants
#define L_SEQ   16384
#define D_IO    2048
#define HEADS   16
#define DHEAD   128
#define KDIM    2048
#define KT      (KDIM / 32)   // 64 K-tiles of BK=32

typedef __attribute__((ext_vector_type(8))) short short8;
typedef __attribute__((ext_vector_type(4))) float floatx4;

typedef const __attribute__((address_space(1))) unsigned int gu_t;
typedef __attribute__((address_space(3))) unsigned int lu_t;

__device__ __forceinline__ unsigned short f2bf(float f) {
  unsigned u = __float_as_uint(f);
  u += 0x7fffu + ((u >> 16) & 1u);   // RNE
  return (unsigned short)(u >> 16);
}
__device__ __forceinline__ float bf2f(unsigned short s) {
  return __uint_as_float(((unsigned)s) << 16);
}

// ---------------- f32 -> bf16 convert (vectorized, grid-stride) ----------------
__global__ __launch_bounds__(256)
void cvt_f32_bf16(const float* __restrict__ x, unsigned short* __restrict__ y, long n)
{
  for (long i = ((long)blockIdx.x * 256 + threadIdx.x) * 8; i < n;
       i += (long)gridDim.x * 256 * 8) {
    const float4 v0 = *(const float4*)(x + i);
    const float4 v1 = *(const float4*)(x + i + 4);
    uint4 r;
    r.x = (unsigned)f2bf(v0.x) | ((unsigned)f2bf(v0.y) << 16);
    r.y = (unsigned)f2bf(v0.z) | ((unsigned)f2bf(v0.w) << 16);
    r.z = (unsigned)f2bf(v1.x) | ((unsigned)f2bf(v1.y) << 16);
    r.w = (unsigned)f2bf(v1.z) | ((unsigned)f2bf(v1.w) << 16);
    *(uint4*)(y + i) = r;
  }
}

// ------------- transpose + convert: S[2048][2048] f32 -> D[2048][2048] bf16 (D = S^T) -------------
__global__ __launch_bounds__(256)
void transpose_cvt(const float* __restrict__ S, unsigned short* __restrict__ D)
{
  __shared__ float tile[32][33];
  const int bn = blockIdx.x * 32;
  const int bk = blockIdx.y * 32;
  const int tx = threadIdx.x, ty = threadIdx.y;  // (32, 8)
  #pragma unroll
  for (int i = 0; i < 32; i += 8)
    tile[ty + i][tx] = S[(size_t)(bk + ty + i) * D_IO + bn + tx];
  __syncthreads();
  #pragma unroll
  for (int i = 0; i < 32; i += 8)
    D[(size_t)(bn + ty + i) * D_IO + bk + tx] = f2bf(tile[tx][ty + i]);
}

// =====================================================================
// 256x256-tile bf16 GEMM, BK=32, 8 waves (2Mx4N), 4-deep LDS pipeline,
// counted vmcnt(8) (never drained in-loop), T2 slot-XOR swizzle,
// T5 setprio around MFMA clusters, T1 XCD block swizzle.
// A: [M][2048] bf16 row-major. B: [N][2048] bf16 row-major (= B^T of math GEMM).
// C = A * B^T. EPI=0: bf16 out, EPI=1: f32 out + bias.
// =====================================================================
template<int EPI>
__global__ __launch_bounds__(512, 2)
void gemm256(const unsigned short* __restrict__ A,
             const unsigned short* __restrict__ B,
             void* __restrict__ Cout,
             const float* __restrict__ bias,
             const int ldc, const int bnShift)
{
  // 4 buffers x (A [256][32] 16KB | B [256][32] 16KB) = 128 KB
  __shared__ unsigned short lds[65536];

  const int t = threadIdx.x, lane = t & 63, wave = t >> 6;
  const int wm = wave >> 2, wn = wave & 3;       // 2 x 4 wave grid; per-wave out 128x64

  // T1: XCD-aware block swizzle (nwg % 8 == 0 for both GEMMs)
  const int nwg  = (int)(gridDim.x * gridDim.y);
  const int flat = (int)(blockIdx.y * gridDim.x + blockIdx.x);
  const int cpx  = nwg >> 3;
  const int swz  = (flat & 7) * cpx + (flat >> 3);
  const int bn = swz & ((1 << bnShift) - 1);
  const int bm = swz >> bnShift;

  const int fr = lane & 15, kq = lane >> 4;
  // T2 read-side swizzle: slot' = kq ^ ((row>>1)&3); row%16==fr for all frags
  const int rslot = ((kq ^ ((fr >> 1) & 3)) * 8);          // shorts

  // staging: per call 512thr x 16B = 128 rows; row = s*128 + (t>>2)
  // inverse swizzle on SOURCE: src k-slot = (t&3) ^ ((row>>1)&3) = (t&3)^((t>>3)&3)
  const int srow  = t >> 2;
  const int sslot = (((t & 3) ^ ((t >> 3) & 3)) * 8);      // elems
  const unsigned short* aSrc = A + (size_t)(bm * 256 + srow) * KDIM + sslot;
  const unsigned short* bSrc = B + (size_t)(bn * 256 + srow) * KDIM + sslot;

  floatx4 acc[8][4];
  #pragma unroll
  for (int m = 0; m < 8; ++m)
    #pragma unroll
    for (int n = 0; n < 4; ++n) acc[m][n] = (floatx4)0.f;

  // dest: wave-uniform base + lane*16 (linear); src: per-lane (pre-swizzled)
#define STAGE_A(tile, ts) do { const int _b = (tile) & 3;                                   \
    __builtin_amdgcn_global_load_lds((gu_t*)(aSrc + (size_t)(ts) * 32),                     \
                                     (lu_t*)(lds + _b * 16384 + wave * 512), 16, 0, 0);     \
    __builtin_amdgcn_global_load_lds((gu_t*)(aSrc + (size_t)128 * KDIM + (size_t)(ts) * 32),\
                                     (lu_t*)(lds + _b * 16384 + 4096 + wave * 512), 16, 0, 0); } while (0)
#define STAGE_B(tile, ts) do { const int _b = (tile) & 3;                                   \
    __builtin_amdgcn_global_load_lds((gu_t*)(bSrc + (size_t)(ts) * 32),                     \
                                     (lu_t*)(lds + _b * 16384 + 8192 + wave * 512), 16, 0, 0); \
    __builtin_amdgcn_global_load_lds((gu_t*)(bSrc + (size_t)128 * KDIM + (size_t)(ts) * 32),\
                                     (lu_t*)(lds + _b * 16384 + 12288 + wave * 512), 16, 0, 0); } while (0)

  // prologue: stage tiles 0,1,2 (4 loads each, A then B)
  STAGE_A(0, 0); STAGE_B(0, 0);
  STAGE_A(1, 1); STAGE_B(1, 1);
  STAGE_A(2, 2); STAGE_B(2, 2);
  asm volatile("s_waitcnt vmcnt(8)" ::: "memory");   // tile 0 landed (8 = tiles 1,2 in flight)
  __builtin_amdgcn_s_barrier();

  for (int tt = 0; tt < KT; ++tt) {
    const int b = tt & 3;
    const int ts = (tt + 3 < KT) ? (tt + 3) : (KT - 1);  // tail: harmless dup re-stage
    const unsigned short* As = lds + b * 16384;
    const unsigned short* Bs = As + 8192;
    short8 av[4], bv[4];

    // ---- phase 0: read A-frags 0-3 + all B-frags; stage A(tt+3); MFMA quadrant 0 ----
    #pragma unroll
    for (int m = 0; m < 4; ++m)
      av[m] = *(const short8*)(As + (wm * 128 + m * 16 + fr) * 32 + rslot);
    #pragma unroll
    for (int n = 0; n < 4; ++n)
      bv[n] = *(const short8*)(Bs + (wn * 64 + n * 16 + fr) * 32 + rslot);
    STAGE_A(tt + 3, ts);
    asm volatile("" ::: "memory");
    __builtin_amdgcn_s_barrier();
    asm volatile("s_waitcnt lgkmcnt(0)" ::: "memory");
    __builtin_amdgcn_s_setprio(1);
    #pragma unroll
    for (int m = 0; m < 4; ++m)
      #pragma unroll
      for (int n = 0; n < 4; ++n)
        acc[m][n] = __builtin_amdgcn_mfma_f32_16x16x32_bf16(av[m], bv[n], acc[m][n], 0, 0, 0);
    __builtin_amdgcn_s_setprio(0);
    asm volatile("" ::: "memory");
    __builtin_amdgcn_s_barrier();

    // ---- phase 1: read A-frags 4-7; stage B(tt+3); counted vmcnt; MFMA quadrant 1 ----
    #pragma unroll
    for (int m = 0; m < 4; ++m)
      av[m] = *(const short8*)(As + (wm * 128 + (m + 4) * 16 + fr) * 32 + rslot);
    STAGE_B(tt + 3, ts);
    // tile tt+1 guaranteed landed; tiles tt+2, tt+3 (8 loads) stay in flight
    asm volatile("s_waitcnt vmcnt(8)" ::: "memory");
    __builtin_amdgcn_s_barrier();
    asm volatile("s_waitcnt lgkmcnt(0)" ::: "memory");
    __builtin_amdgcn_s_setprio(1);
    #pragma unroll
    for (int m = 0; m < 4; ++m)
      #pragma unroll
      for (int n = 0; n < 4; ++n)
        acc[m + 4][n] = __builtin_amdgcn_mfma_f32_16x16x32_bf16(av[m], bv[n], acc[m + 4][n], 0, 0, 0);
    __builtin_amdgcn_s_setprio(0);
    asm volatile("" ::: "memory");
    __builtin_amdgcn_s_barrier();
  }
#undef STAGE_A
#undef STAGE_B

  // epilogue: C/D layout col = lane&15, row = (lane>>4)*4 + reg
  const int crow0 = bm * 256 + wm * 128 + kq * 4;
  const int ccol0 = bn * 256 + wn * 64 + fr;
  if (EPI == 0) {
    unsigned short* C = (unsigned short*)Cout;
    #pragma unroll
    for (int m = 0; m < 8; ++m)
      #pragma unroll
      for (int n = 0; n < 4; ++n)
        #pragma unroll
        for (int r = 0; r < 4; ++r)
          C[(size_t)(crow0 + m * 16 + r) * ldc + ccol0 + n * 16] = f2bf(acc[m][n][r]);
  } else {
    float* C = (float*)Cout;
    #pragma unroll
    for (int n = 0; n < 4; ++n) {
      const float bv_ = bias[ccol0 + n * 16];
      #pragma unroll
      for (int m = 0; m < 8; ++m)
        #pragma unroll
        for (int r = 0; r < 4; ++r)
          C[(size_t)(crow0 + m * 16 + r) * ldc + ccol0 + n * 16] = acc[m][n][r] + bv_;
    }
  }
}

// ---------------- sliding-window attention pool ----------------
__global__ __launch_bounds__(256)
void winpool(const unsigned short* __restrict__ KV,
             const float* __restrict__ Q,
             unsigned short* __restrict__ P)
{
  const int lane = threadIdx.x & 63, wid = threadIdx.x >> 6;
  const int t = blockIdx.x * 4 + wid;
  const int h = blockIdx.y;
  const float qx = Q[h * DHEAD + lane * 2];
  const float qy = Q[h * DHEAD + lane * 2 + 1];
  const float scale = 0.08838834764831845f;  // 1/sqrt(128)

  float s[4];
  #pragma unroll
  for (int w = 0; w < 4; ++w) {
    const int idx = t - 3 + w;
    float part = 0.f;
    if (idx >= 0) {
      const unsigned kk = *(const unsigned*)(KV + (size_t)idx * 4096 + h * DHEAD + lane * 2);
      part = qx * bf2f((unsigned short)(kk & 0xffffu)) +
             qy * bf2f((unsigned short)(kk >> 16));
    }
    #pragma unroll
    for (int off = 32; off > 0; off >>= 1) part += __shfl_xor(part, off);
    s[w] = part * scale;
  }
  float mx = -3.0e38f;
  #pragma unroll
  for (int w = 0; w < 4; ++w) if (t - 3 + w >= 0) mx = fmaxf(mx, s[w]);
  float p[4], sum = 0.f;
  #pragma unroll
  for (int w = 0; w < 4; ++w) {
    p[w] = (t - 3 + w >= 0) ? expf(s[w] - mx) : 0.f;
    sum += p[w];
  }
  const float inv = 1.f / sum;

  float o0 = 0.f, o1 = 0.f;
  #pragma unroll
  for (int w = 0; w < 4; ++w) {
    const int idx = t - 3 + w;
    if (idx >= 0) {
      const unsigned vv = *(const unsigned*)(KV + (size_t)idx * 4096 + 2048 + h * DHEAD + lane * 2);
      o0 += p[w] * bf2f((unsigned short)(vv & 0xffffu));
      o1 += p[w] * bf2f((unsigned short)(vv >> 16));
    }
  }
  o0 *= inv; o1 *= inv;
  const unsigned outw = ((unsigned)f2bf(o1) << 16) | (unsigned)f2bf(o0);
  *(unsigned*)(P + (size_t)t * D_IO + h * DHEAD + lane * 2) = outw;
}

// ---------------- launch ----------------
extern "C" void kernel_launch(void* const* d_in, const int* in_sizes, int n_in,
                              void* d_out, int out_size, void* d_ws, size_t ws_size,
                              hipStream_t stream)
{
  const float* e_seq = (const float*)d_in[0];
  const float* q     = (const float*)d_in[1];
  const float* Wk    = (const float*)d_in[2];
  const float* Wv    = (const float*)d_in[3];
  const float* Wo    = (const float*)d_in[4];
  const float* bo    = (const float*)d_in[5];
  float* out = (float*)d_out;

  char* ws = (char*)d_ws;
  unsigned short* Ebf  = (unsigned short*)ws;                                     // 64 MB (E bf16; reused as pooled)
  unsigned short* KV   = (unsigned short*)(ws + 67108864);                        // 128 MB
  unsigned short* Wkvt = (unsigned short*)(ws + 67108864 + 134217728);            // 16 MB
  unsigned short* Wot  = (unsigned short*)(ws + 67108864 + 134217728 + 16777216); // 8 MB

  cvt_f32_bf16<<<2048, 256, 0, stream>>>(e_seq, Ebf, (long)L_SEQ * D_IO);
  dim3 tb(32, 8);
  transpose_cvt<<<dim3(64, 64), tb, 0, stream>>>(Wk, Wkvt);
  transpose_cvt<<<dim3(64, 64), tb, 0, stream>>>(Wv, Wkvt + (size_t)D_IO * D_IO);
  transpose_cvt<<<dim3(64, 64), tb, 0, stream>>>(Wo, Wot);

  // KV = E * [Wk|Wv]   (M=16384, N=4096, K=2048), bf16 out
  gemm256<0><<<dim3(16, 64), 512, 0, stream>>>(Ebf, Wkvt, KV, nullptr, 4096, 4);

  // pooled (into Ebf, no longer needed)
  winpool<<<dim3(L_SEQ / 4, HEADS), 256, 0, stream>>>(KV, q, Ebf);

  // out = pooled * Wo + bo   (M=16384, N=2048, K=2048), f32 out + bias
  gemm256<1><<<dim3(8, 64), 512, 0, stream>>>(Ebf, Wot, out, bo, 2048, 3);
}